// Round 1
// baseline (430.957 us; speedup 1.0000x reference)
//
#include <hip/hip_runtime.h>
#include <math.h>

constexpr int H = 512, W = 512;
constexpr int N_ANGLES = 360;
constexpr int N_DET = 736;
constexpr int N_STEPS = 725;                 // ceil(hypot(512,512))
constexpr int SINO_SIZE = N_ANGLES * N_DET;  // 264960

// ---------------------------------------------------------------------------
// Kernel 1: updated_reco = x + reco  (float4-vectorized, 1 MB total)
// ---------------------------------------------------------------------------
__global__ void add_kernel(const float4* __restrict__ x,
                           const float4* __restrict__ reco,
                           float4* __restrict__ out) {
    int i = blockIdx.x * blockDim.x + threadIdx.x;
    float4 a = x[i];
    float4 b = reco[i];
    out[i] = make_float4(a.x + b.x, a.y + b.y, a.z + b.z, a.w + b.w);
}

// ---------------------------------------------------------------------------
// Kernel 2: ray-driven forward projection. One thread per (angle, detector).
// ---------------------------------------------------------------------------
__global__ __launch_bounds__(256) void radon_kernel(const float* __restrict__ img,
                                                    const float* __restrict__ angles,
                                                    float* __restrict__ sino) {
    const int d = blockIdx.x * blockDim.x + threadIdx.x;
    const int a = blockIdx.y;
    if (d >= N_DET) return;

    const float theta = angles[a];
    const float c = cosf(theta);
    const float s = sinf(theta);
    const float cx = (W - 1) * 0.5f;            // 255.5
    const float cy = (H - 1) * 0.5f;            // 255.5
    const float u = (float)d - (N_DET - 1) * 0.5f;
    const float bx = -s * u;                    // xs = bx + c*t + cx
    const float by =  c * u;                    // ys = by + s*t + cy
    const float t_off = (N_STEPS - 1) * 0.5f;   // 362

    // Clip the sample range: contribution is exactly zero unless
    // px in (-1, W) and py in (-1, H). Use closed [-1, W]/[-1, H] + slack.
    float tmin = -1e30f, tmax = 1e30f;
    {
        float lo = -1.0f - cx - bx;
        float hi = (float)W - cx - bx;
        if (fabsf(c) > 1e-12f) {
            float t0 = lo / c, t1 = hi / c;
            tmin = fmaxf(tmin, fminf(t0, t1));
            tmax = fminf(tmax, fmaxf(t0, t1));
        } else if (lo > 0.0f || hi < 0.0f) {
            tmax = -2e30f;  // ray never enters in x -> empty
        }
    }
    {
        float lo = -1.0f - cy - by;
        float hi = (float)H - cy - by;
        if (fabsf(s) > 1e-12f) {
            float t0 = lo / s, t1 = hi / s;
            tmin = fmaxf(tmin, fminf(t0, t1));
            tmax = fminf(tmax, fmaxf(t0, t1));
        } else if (lo > 0.0f || hi < 0.0f) {
            tmax = -2e30f;
        }
    }

    // k range (with +/-1 slack for float rounding), clamped to valid ints
    int kmin = (int)fminf(725.0f, fmaxf(0.0f, ceilf(tmin + t_off) - 1.0f));
    int kmax = (int)fmaxf(-1.0f, fminf((float)(N_STEPS - 1), floorf(tmax + t_off) + 1.0f));

    float acc = 0.0f;
    for (int k = kmin; k <= kmax; ++k) {
        float t = (float)k - t_off;
        float px = fmaf(c, t, bx) + cx;
        float py = fmaf(s, t, by) + cy;
        float fx = floorf(px);
        float fy = floorf(py);
        float wx = px - fx;
        float wy = py - fy;
        int xi = (int)fx;
        int yi = (int)fy;

        float v00, v01, v10, v11;
        if (xi >= 0 && yi >= 0 && xi < W - 1 && yi < H - 1) {
            // fully interior footprint (common case)
            const float* p = img + yi * W + xi;
            v00 = p[0];
            v01 = p[1];
            v10 = p[W];
            v11 = p[W + 1];
        } else {
            bool xin0 = (xi >= 0) && (xi < W);
            bool xin1 = (xi + 1 >= 0) && (xi + 1 < W);
            bool yin0 = (yi >= 0) && (yi < H);
            bool yin1 = (yi + 1 >= 0) && (yi + 1 < H);
            int xc0 = min(max(xi, 0), W - 1);
            int xc1 = min(max(xi + 1, 0), W - 1);
            int yc0 = min(max(yi, 0), H - 1);
            int yc1 = min(max(yi + 1, 0), H - 1);
            v00 = (xin0 && yin0) ? img[yc0 * W + xc0] : 0.0f;
            v01 = (xin1 && yin0) ? img[yc0 * W + xc1] : 0.0f;
            v10 = (xin0 && yin1) ? img[yc1 * W + xc0] : 0.0f;
            v11 = (xin1 && yin1) ? img[yc1 * W + xc1] : 0.0f;
        }

        acc += v00 * (1.0f - wx) * (1.0f - wy)
             + v01 * wx * (1.0f - wy)
             + v10 * (1.0f - wx) * wy
             + v11 * wx * wy;
    }

    sino[a * N_DET + d] = acc;  // * STEP (=1)
}

// ---------------------------------------------------------------------------
extern "C" void kernel_launch(void* const* d_in, const int* in_sizes, int n_in,
                              void* d_out, int out_size, void* d_ws, size_t ws_size,
                              hipStream_t stream) {
    const float* x      = (const float*)d_in[0];
    const float* reco   = (const float*)d_in[1];
    const float* angles = (const float*)d_in[2];

    float* sino    = (float*)d_out;              // (360, 736)
    float* updated = (float*)d_out + SINO_SIZE;  // (512, 512)

    // updated_reco = x + reco
    int n4 = (H * W) / 4;  // 65536 float4s
    add_kernel<<<n4 / 256, 256, 0, stream>>>(
        (const float4*)x, (const float4*)reco, (float4*)updated);

    // forward projection
    dim3 grid((N_DET + 255) / 256, N_ANGLES);
    radon_kernel<<<grid, 256, 0, stream>>>(updated, angles, sino);
}

// Round 2
// 267.535 us; speedup vs baseline: 1.6108x; 1.6108x over previous
//
#include <hip/hip_runtime.h>
#include <math.h>

constexpr int H = 512, W = 512;
constexpr int N_ANGLES = 360;
constexpr int N_DET = 736;
constexpr int N_STEPS = 725;                 // ceil(hypot(512,512))
constexpr int SINO_SIZE = N_ANGLES * N_DET;  // 264960

// ---------------------------------------------------------------------------
// Kernel 1: updated_reco = x + reco  (float4-vectorized, 1 MB total)
// ---------------------------------------------------------------------------
__global__ void add_kernel(const float4* __restrict__ x,
                           const float4* __restrict__ reco,
                           float4* __restrict__ out) {
    int i = blockIdx.x * blockDim.x + threadIdx.x;
    float4 a = x[i];
    float4 b = reco[i];
    out[i] = make_float4(a.x + b.x, a.y + b.y, a.z + b.z, a.w + b.w);
}

// ---------------------------------------------------------------------------
// Kernel 2: forward projection. Each wave owns an 8x8 (det x k) footprint:
//   lane = dl + 8*kl,  dl = detector-lane (0..7), kl = k-lane (0..7).
// Lane (dl,kl) accumulates samples k = kminw + kl + 8*i for detector d(dl).
// Final shfl_xor reduce over kl (masks 8,16,32); kl==0 lane writes.
// 2-D footprint keeps the wave's gather addresses in a ~11x11 px patch for
// every angle -> ~5x fewer cache-line transactions than a 64-det line.
// ---------------------------------------------------------------------------
__global__ __launch_bounds__(256) void radon_kernel(const float* __restrict__ img,
                                                    const float* __restrict__ angles,
                                                    float* __restrict__ sino) {
    const int lane = threadIdx.x & 63;
    const int wave = threadIdx.x >> 6;   // 0..3
    const int dl   = lane & 7;           // detector lane
    const int kl   = lane >> 3;          // k lane
    const int a    = blockIdx.y;
    const int d    = blockIdx.x * 32 + wave * 8 + dl;   // 23*32 = 736 exact

    const float theta = angles[a];
    const float c = cosf(theta);
    const float s = sinf(theta);
    const float cx = (W - 1) * 0.5f;            // 255.5
    const float cy = (H - 1) * 0.5f;            // 255.5
    const float u = (float)d - (N_DET - 1) * 0.5f;
    const float bx = -s * u;                    // xs = bx + c*t + cx
    const float by =  c * u;                    // ys = by + s*t + cy
    const float t_off = (N_STEPS - 1) * 0.5f;   // 362

    // Exact nonzero-contribution window: px in (-1, W), py in (-1, H).
    float tmin = -1e30f, tmax = 1e30f;
    {
        float lo = -1.0f - cx - bx;
        float hi = (float)W - cx - bx;
        if (fabsf(c) > 1e-12f) {
            float t0 = lo / c, t1 = hi / c;
            tmin = fmaxf(tmin, fminf(t0, t1));
            tmax = fminf(tmax, fmaxf(t0, t1));
        } else if (lo > 0.0f || hi < 0.0f) {
            tmax = -2e30f;
        }
    }
    {
        float lo = -1.0f - cy - by;
        float hi = (float)H - cy - by;
        if (fabsf(s) > 1e-12f) {
            float t0 = lo / s, t1 = hi / s;
            tmin = fmaxf(tmin, fminf(t0, t1));
            tmax = fminf(tmax, fmaxf(t0, t1));
        } else if (lo > 0.0f || hi < 0.0f) {
            tmax = -2e30f;
        }
    }

    int kmin = (int)fminf(725.0f, fmaxf(0.0f, ceilf(tmin + t_off) - 1.0f));
    int kmax = (int)fmaxf(-1.0f, fminf((float)(N_STEPS - 1), floorf(tmax + t_off) + 1.0f));

    // Wave-union k range over the 8 detectors (reduce across dl bits 1,2,4).
    // Out-of-own-range k samples land outside the image -> masked to zero by
    // the boundary path, so using the union is exact.
    int kminw = kmin, kmaxw = kmax;
    kminw = min(kminw, __shfl_xor(kminw, 1));
    kminw = min(kminw, __shfl_xor(kminw, 2));
    kminw = min(kminw, __shfl_xor(kminw, 4));
    kmaxw = max(kmaxw, __shfl_xor(kmaxw, 1));
    kmaxw = max(kmaxw, __shfl_xor(kmaxw, 2));
    kmaxw = max(kmaxw, __shfl_xor(kmaxw, 4));

    float acc = 0.0f;
    #pragma unroll 2
    for (int k = kminw + kl; k <= kmaxw; k += 8) {
        float t = (float)k - t_off;
        float px = fmaf(c, t, bx) + cx;
        float py = fmaf(s, t, by) + cy;
        float fx = floorf(px);
        float fy = floorf(py);
        float wx = px - fx;
        float wy = py - fy;
        int xi = (int)fx;
        int yi = (int)fy;

        float v00, v01, v10, v11;
        if (xi >= 0 && yi >= 0 && xi < W - 1 && yi < H - 1) {
            const float* p = img + yi * W + xi;
            v00 = p[0];
            v01 = p[1];
            v10 = p[W];
            v11 = p[W + 1];
        } else {
            bool xin0 = (xi >= 0) && (xi < W);
            bool xin1 = (xi + 1 >= 0) && (xi + 1 < W);
            bool yin0 = (yi >= 0) && (yi < H);
            bool yin1 = (yi + 1 >= 0) && (yi + 1 < H);
            int xc0 = min(max(xi, 0), W - 1);
            int xc1 = min(max(xi + 1, 0), W - 1);
            int yc0 = min(max(yi, 0), H - 1);
            int yc1 = min(max(yi + 1, 0), H - 1);
            v00 = (xin0 && yin0) ? img[yc0 * W + xc0] : 0.0f;
            v01 = (xin1 && yin0) ? img[yc0 * W + xc1] : 0.0f;
            v10 = (xin0 && yin1) ? img[yc1 * W + xc0] : 0.0f;
            v11 = (xin1 && yin1) ? img[yc1 * W + xc1] : 0.0f;
        }

        // bilinear via 3 lerps (fma form)
        float top = fmaf(wx, v01 - v00, v00);
        float bot = fmaf(wx, v11 - v10, v10);
        acc = fmaf(wy, bot - top, acc + top);
    }

    // Reduce the 8 k-lanes (same detector): kl lives in lane bits 3,4,5.
    acc += __shfl_xor(acc, 8);
    acc += __shfl_xor(acc, 16);
    acc += __shfl_xor(acc, 32);

    if (kl == 0) sino[a * N_DET + d] = acc;
}

// ---------------------------------------------------------------------------
extern "C" void kernel_launch(void* const* d_in, const int* in_sizes, int n_in,
                              void* d_out, int out_size, void* d_ws, size_t ws_size,
                              hipStream_t stream) {
    const float* x      = (const float*)d_in[0];
    const float* reco   = (const float*)d_in[1];
    const float* angles = (const float*)d_in[2];

    float* sino    = (float*)d_out;              // (360, 736)
    float* updated = (float*)d_out + SINO_SIZE;  // (512, 512)

    int n4 = (H * W) / 4;
    add_kernel<<<n4 / 256, 256, 0, stream>>>(
        (const float4*)x, (const float4*)reco, (float4*)updated);

    dim3 grid(N_DET / 32, N_ANGLES);   // (23, 360)
    radon_kernel<<<grid, 256, 0, stream>>>(updated, angles, sino);
}

// Round 3
// 195.814 us; speedup vs baseline: 2.2008x; 1.3663x over previous
//
#include <hip/hip_runtime.h>
#include <math.h>

constexpr int H = 512, W = 512;
constexpr int N_ANGLES = 360;
constexpr int N_DET = 736;
constexpr int N_STEPS = 725;                 // ceil(hypot(512,512))
constexpr int SINO_SIZE = N_ANGLES * N_DET;  // 264960

constexpr int DET_TILE = 32;
constexpr int K_TILE   = 64;
// Worst-case bbox: (63|c|+31|s|+3)*(31|c|+63|s|+3) + odd-pitch pad <= ~4900
constexpr int TILE_CAP = 4992;               // floats = 19968 B

// ---------------------------------------------------------------------------
// Kernel 1: updated_reco = x + reco
// ---------------------------------------------------------------------------
__global__ void add_kernel(const float4* __restrict__ x,
                           const float4* __restrict__ reco,
                           float4* __restrict__ out) {
    int i = blockIdx.x * blockDim.x + threadIdx.x;
    float4 a = x[i];
    float4 b = reco[i];
    out[i] = make_float4(a.x + b.x, a.y + b.y, a.z + b.z, a.w + b.w);
}

// ---------------------------------------------------------------------------
// Kernel 2: LDS-tiled forward projection.
// Block = (angle, 32 detectors). k loops in 64-sample tiles; each tile's
// image-space bounding box (<= ~70x70 px at any angle) is staged to LDS,
// then samples gather from LDS (banked scratchpad, no cache-line penalty).
// Thread map: dl = tid&31 (detector), klr = tid>>5 (k residue 0..7).
// ---------------------------------------------------------------------------
__global__ __launch_bounds__(256) void radon_kernel(const float* __restrict__ img,
                                                    const float* __restrict__ angles,
                                                    float* __restrict__ sino) {
    __shared__ float tile[TILE_CAP];

    const int tid = threadIdx.x;
    const int dl  = tid & 31;           // detector lane
    const int klr = tid >> 5;           // k residue 0..7
    const int a   = blockIdx.y;
    const int d0  = blockIdx.x * DET_TILE;
    const int d   = d0 + dl;

    const float theta = angles[a];
    const float c = cosf(theta);
    const float s = sinf(theta);
    const float cx = (W - 1) * 0.5f;            // 255.5
    const float cy = (H - 1) * 0.5f;            // 255.5
    const float u  = (float)d - (N_DET - 1) * 0.5f;
    const float bx = -s * u;                    // xs = bx + c*t + cx
    const float by =  c * u;                    // ys = by + s*t + cy
    const float t_off = (N_STEPS - 1) * 0.5f;   // 362

    // Exact nonzero-contribution window: px in (-1, W), py in (-1, H).
    float tmin = -1e30f, tmax = 1e30f;
    {
        float lo = -1.0f - cx - bx;
        float hi = (float)W - cx - bx;
        if (fabsf(c) > 1e-12f) {
            float t0 = lo / c, t1 = hi / c;
            tmin = fmaxf(tmin, fminf(t0, t1));
            tmax = fminf(tmax, fmaxf(t0, t1));
        } else if (lo > 0.0f || hi < 0.0f) {
            tmax = -2e30f;
        }
    }
    {
        float lo = -1.0f - cy - by;
        float hi = (float)H - cy - by;
        if (fabsf(s) > 1e-12f) {
            float t0 = lo / s, t1 = hi / s;
            tmin = fmaxf(tmin, fminf(t0, t1));
            tmax = fminf(tmax, fmaxf(t0, t1));
        } else if (lo > 0.0f || hi < 0.0f) {
            tmax = -2e30f;
        }
    }

    int kmin = (int)fminf(725.0f, fmaxf(0.0f, ceilf(tmin + t_off) - 1.0f));
    int kmax = (int)fmaxf(-1.0f, fminf((float)(N_STEPS - 1), floorf(tmax + t_off) + 1.0f));

    // Union over the 32 detectors of the block. Lanes 0..31 and 32..63 hold
    // the same dl sequence, so xor masks 1..16 give the full-block union on
    // every lane, identically in all 4 waves.
    int kminw = kmin, kmaxw = kmax;
    #pragma unroll
    for (int m = 1; m <= 16; m <<= 1) {
        kminw = min(kminw, __shfl_xor(kminw, m));
        kmaxw = max(kmaxw, __shfl_xor(kmaxw, m));
    }

    const float u_c = (float)d0 + 15.5f - (N_DET - 1) * 0.5f;  // tile-center u
    const float ac = fabsf(c), as = fabsf(s);

    float acc = 0.0f;

    for (int k0 = kminw; k0 <= kmaxw; k0 += K_TILE) {
        const int k1 = min(k0 + K_TILE - 1, kmaxw);
        const float t0f = (float)k0 - t_off;
        const float t1f = (float)k1 - t_off;
        const float tc  = 0.5f * (t0f + t1f);
        // bbox of sample positions for (u in [u_c-15.5, u_c+15.5], t in [t0,t1])
        const float xc = fmaf(c, tc, -s * u_c) + cx;
        const float yc = fmaf(s, tc,  c * u_c) + cy;
        const float hx = 0.5f * (ac * (t1f - t0f) + as * 31.0f) + 0.5f;
        const float hy = 0.5f * (as * (t1f - t0f) + ac * 31.0f) + 0.5f;
        const int x0 = max(0, (int)floorf(xc - hx));
        const int x1 = min(W - 1, (int)floorf(xc + hx) + 1);
        const int y0 = max(0, (int)floorf(yc - hy));
        const int y1 = min(H - 1, (int)floorf(yc + hy) + 1);
        if (x0 > x1 || y0 > y1) continue;   // block-uniform
        const int bw = x1 - x0 + 1;
        const int bh = y1 - y0 + 1;
        const int pitch = bw | 1;           // odd pitch -> bank spread

        // stage bbox rows (coalesced 64-lane row segments)
        {
            const int ty = tid >> 6;        // 0..3
            const int tx = tid & 63;
            for (int y = ty; y < bh; y += 4) {
                const float* src = img + (y0 + y) * W + x0;
                float* dst = tile + y * pitch;
                for (int x = tx; x < bw; x += 64)
                    dst[x] = src[x];
            }
        }
        __syncthreads();

        // sample from LDS
        for (int k = k0 + klr; k <= k1; k += 8) {
            float t  = (float)k - t_off;
            float px = fmaf(c, t, bx) + cx;
            float py = fmaf(s, t, by) + cy;
            float fx = floorf(px);
            float fy = floorf(py);
            float wx = px - fx;
            float wy = py - fy;
            int xi = (int)fx;
            int yi = (int)fy;
            int idx = (yi - y0) * pitch + (xi - x0);

            float v00, v01, v10, v11;
            if (xi >= 0 && yi >= 0 && xi < W - 1 && yi < H - 1) {
                v00 = tile[idx];
                v01 = tile[idx + 1];
                v10 = tile[idx + pitch];
                v11 = tile[idx + pitch + 1];
            } else {
                bool xin0 = (xi >= 0) && (xi < W);
                bool xin1 = (xi + 1 >= 0) && (xi + 1 < W);
                bool yin0 = (yi >= 0) && (yi < H);
                bool yin1 = (yi + 1 >= 0) && (yi + 1 < H);
                // any in-image corner is inside the staged bbox by construction
                v00 = (xin0 && yin0) ? tile[idx] : 0.0f;
                v01 = (xin1 && yin0) ? tile[idx + 1] : 0.0f;
                v10 = (xin0 && yin1) ? tile[idx + pitch] : 0.0f;
                v11 = (xin1 && yin1) ? tile[idx + pitch + 1] : 0.0f;
            }

            float top = fmaf(wx, v01 - v00, v00);
            float bot = fmaf(wx, v11 - v10, v10);
            acc = fmaf(wy, bot - top, acc + top);
        }
        __syncthreads();
    }

    // Reduce 8 k-residues per detector: pair within wave, then across waves.
    acc += __shfl_xor(acc, 32);
    if ((tid & 63) < 32)
        tile[(tid >> 6) * 32 + dl] = acc;   // tile reuse: safe, all reads synced
    __syncthreads();
    if (tid < 32) {
        float r = tile[tid] + tile[tid + 32] + tile[tid + 64] + tile[tid + 96];
        sino[a * N_DET + d0 + tid] = r;
    }
}

// ---------------------------------------------------------------------------
extern "C" void kernel_launch(void* const* d_in, const int* in_sizes, int n_in,
                              void* d_out, int out_size, void* d_ws, size_t ws_size,
                              hipStream_t stream) {
    const float* x      = (const float*)d_in[0];
    const float* reco   = (const float*)d_in[1];
    const float* angles = (const float*)d_in[2];

    float* sino    = (float*)d_out;              // (360, 736)
    float* updated = (float*)d_out + SINO_SIZE;  // (512, 512)

    int n4 = (H * W) / 4;
    add_kernel<<<n4 / 256, 256, 0, stream>>>(
        (const float4*)x, (const float4*)reco, (float4*)updated);

    dim3 grid(N_DET / DET_TILE, N_ANGLES);   // (23, 360)
    radon_kernel<<<grid, 256, 0, stream>>>(updated, angles, sino);
}

// Round 4
// 168.446 us; speedup vs baseline: 2.5584x; 1.1625x over previous
//
#include <hip/hip_runtime.h>
#include <math.h>

constexpr int H = 512, W = 512;
constexpr int N_ANGLES = 360;
constexpr int N_DET = 736;
constexpr int N_STEPS = 725;                 // ceil(hypot(512,512))
constexpr int SINO_SIZE = N_ANGLES * N_DET;  // 264960

constexpr int DET_TILE = 64;
constexpr int K_TILE   = 64;
constexpr int PITCH    = 98;   // floats; even (8B chunks), 98 mod 32 = 2 (bank spread)
constexpr int ROWS     = 94;   // max bh is 93 (proof in bbox math) + 1 margin
constexpr int CHUNKS   = PITCH / 2;  // 49 float2 per row
// LDS: 94*98*4 = 36848 B -> 4 blocks/CU (147 KB of 160) @ 512 thr = 32 waves/CU

// ---------------------------------------------------------------------------
// Kernel 1: updated_reco = x + reco
// ---------------------------------------------------------------------------
__global__ void add_kernel(const float4* __restrict__ x,
                           const float4* __restrict__ reco,
                           float4* __restrict__ out) {
    int i = blockIdx.x * blockDim.x + threadIdx.x;
    float4 a = x[i];
    float4 b = reco[i];
    out[i] = make_float4(a.x + b.x, a.y + b.y, a.z + b.z, a.w + b.w);
}

// ---------------------------------------------------------------------------
// Kernel 2: forward projection, zero-border LDS tiles, branch-free inner loop.
// Block = (angle, 64 detectors), 512 threads.
// Wave footprint: 16 detectors x 4 k-steps (2-D patch -> bank spread).
//   w = tid>>6, l = tid&63;  det = 16*(w&3) + (l&15);  klr = 4*(w>>2) + (l>>4)
// Per k-tile (64 steps): stage the FULL sample-parallelogram bbox into LDS,
// with 0 for out-of-image pixels. All 4 bilinear corners of every sample are
// then in LDS with exact values -> no bounds checks in the inner loop.
// ---------------------------------------------------------------------------
__global__ __launch_bounds__(512, 8) void radon_kernel(const float* __restrict__ img,
                                                       const float* __restrict__ angles,
                                                       float* __restrict__ sino) {
    __shared__ float tile[ROWS * PITCH];

    const int tid = threadIdx.x;
    const int w   = tid >> 6;
    const int l   = tid & 63;
    const int dt_ = 16 * (w & 3) + (l & 15);   // detector within tile
    const int klr = 4 * (w >> 2) + (l >> 4);   // k residue 0..7
    const int a   = blockIdx.y;
    const int d0  = blockIdx.x * DET_TILE;

    const float theta = angles[a];
    const float c = cosf(theta);
    const float s = sinf(theta);
    const float ac = fabsf(c), as = fabsf(s);
    const float cx = (W - 1) * 0.5f;            // 255.5
    const float cy = (H - 1) * 0.5f;            // 255.5
    const float t_off = (N_STEPS - 1) * 0.5f;   // 362

    const float u   = (float)(d0 + dt_) - (N_DET - 1) * 0.5f;
    const float bxu = cx - s * u;               // px = c*t + bxu
    const float byu = cy + c * u;               // py = s*t + byu

    // ---- conservative block k-window via interval arithmetic over u ----
    const float uLo = (float)d0 - (N_DET - 1) * 0.5f;
    const float uHi = uLo + (DET_TILE - 1);
    float su0 = s * uLo, su1 = s * uHi;
    float smin = fminf(su0, su1), smax = fmaxf(su0, su1);
    float cu0 = c * uLo, cu1 = c * uHi;
    float cmin = fminf(cu0, cu1), cmax = fmaxf(cu0, cu1);

    float tmin = -1e30f, tmax = 1e30f;
    {   // exists u: px in (-1, W)  <=>  c*t in (xlo, xhi)
        float xlo = -1.0f - cx + smin;
        float xhi = (float)W - cx + smax;
        if (ac > 1e-12f) {
            float t0 = xlo / c, t1 = xhi / c;
            tmin = fmaxf(tmin, fminf(t0, t1));
            tmax = fminf(tmax, fmaxf(t0, t1));
        } else if (xlo > 0.0f || xhi < 0.0f) {
            tmax = -2e30f;
        }
    }
    {   // exists u: py in (-1, H)  <=>  s*t in (ylo, yhi)
        float ylo = -1.0f - cy - cmax;
        float yhi = (float)H - cy - cmin;
        if (as > 1e-12f) {
            float t0 = ylo / s, t1 = yhi / s;
            tmin = fmaxf(tmin, fminf(t0, t1));
            tmax = fminf(tmax, fmaxf(t0, t1));
        } else if (ylo > 0.0f || yhi < 0.0f) {
            tmax = -2e30f;
        }
    }
    const int kminU = (int)fminf(725.0f, fmaxf(0.0f, ceilf(tmin + t_off) - 1.0f));
    const int kmaxU = (int)fmaxf(-1.0f, fminf((float)(N_STEPS - 1), floorf(tmax + t_off) + 1.0f));

    const float ucf = uLo + 0.5f * (DET_TILE - 1);
    const float dx8 = 8.0f * c;
    const float dy8 = 8.0f * s;

    float acc = 0.0f;

    for (int k0 = kminU; k0 <= kmaxU; k0 += K_TILE) {
        const int k1 = min(k0 + K_TILE - 1, kmaxU);
        const float t0f = (float)k0 - t_off;
        const float t1f = (float)k1 - t_off;
        const float dt  = t1f - t0f;
        const float tc  = 0.5f * (t0f + t1f);
        // bbox of ALL sample positions for (u in tile, t in [t0,t1]) + slack
        const float xc = fmaf(c, tc, cx) - s * ucf;
        const float yc = fmaf(s, tc, cy) + c * ucf;
        const float hx = fmaf(0.5f * ac, dt, 0.5f * (DET_TILE - 1) * as) + 0.5f;
        const float hy = fmaf(0.5f * as, dt, 0.5f * (DET_TILE - 1) * ac) + 0.5f;
        const int x0 = ((int)floorf(xc - hx)) & ~1;         // even (8B chunks)
        const int y0 = (int)floorf(yc - hy);
        const int y1 = (int)floorf(yc + hy) + 1;            // covers yi+1
        const int bh = min(y1 - y0 + 1, ROWS);

        // ---- stage bbox rows as float2 chunks; 0 outside the image ----
        {
            const int total = bh * CHUNKS;
            for (int i = tid; i < total; i += 512) {
                int r  = i / CHUNKS;                // const-divisor magic mul
                int ch = i - r * CHUNKS;
                int gx = x0 + 2 * ch;
                int gy = y0 + r;
                float2 v = make_float2(0.0f, 0.0f);
                if ((unsigned)gy < (unsigned)H) {
                    const float* row = img + gy * W;
                    if (gx >= 0 && gx + 1 < W) {
                        v = *(const float2*)(row + gx);
                    } else {
                        if ((unsigned)gx < (unsigned)W)       v.x = row[gx];
                        if ((unsigned)(gx + 1) < (unsigned)W) v.y = row[gx + 1];
                    }
                }
                *(float2*)(tile + r * PITCH + 2 * ch) = v;  // 8B aligned
            }
        }
        __syncthreads();

        // ---- branch-free sampling from LDS ----
        const int kst = k0 + klr;
        float px = fmaf(c, (float)kst - t_off, bxu) - (float)x0;
        float py = fmaf(s, (float)kst - t_off, byu) - (float)y0;
        #pragma unroll 2
        for (int k = kst; k <= k1; k += 8) {
            float fx = floorf(px);
            float fy = floorf(py);
            float wx = px - fx;
            float wy = py - fy;
            int xi = (int)fx;
            int yi = (int)fy;
            int idx = __mul24(yi, PITCH) + xi;
            float v00 = tile[idx];
            float v01 = tile[idx + 1];          // ds_read2_b32 (0,1)
            float v10 = tile[idx + PITCH];
            float v11 = tile[idx + PITCH + 1];  // ds_read2_b32 (98,99)
            float top = fmaf(wx, v01 - v00, v00);
            float bot = fmaf(wx, v11 - v10, v10);
            acc = fmaf(wy, bot - top, acc + top);
            px += dx8;
            py += dy8;
        }
        __syncthreads();
    }

    // ---- reduce 8 k-residues per detector ----
    // within wave: sum over l>>4 (lane bits 4,5)
    acc += __shfl_xor(acc, 16);
    acc += __shfl_xor(acc, 32);
    // across waves w and w+4 (same det group) via LDS scratch
    float* scratch = tile;   // safe: all tile reads behind the last __syncthreads
    if (l < 16) scratch[w * 16 + l] = acc;
    __syncthreads();
    if (tid < DET_TILE) {
        int g  = tid >> 4;
        int dd = tid & 15;
        float r = scratch[g * 16 + dd] + scratch[(g + 4) * 16 + dd];
        int dglob = d0 + tid;
        if (dglob < N_DET) sino[a * N_DET + dglob] = r;
    }
}

// ---------------------------------------------------------------------------
extern "C" void kernel_launch(void* const* d_in, const int* in_sizes, int n_in,
                              void* d_out, int out_size, void* d_ws, size_t ws_size,
                              hipStream_t stream) {
    const float* x      = (const float*)d_in[0];
    const float* reco   = (const float*)d_in[1];
    const float* angles = (const float*)d_in[2];

    float* sino    = (float*)d_out;              // (360, 736)
    float* updated = (float*)d_out + SINO_SIZE;  // (512, 512)

    int n4 = (H * W) / 4;
    add_kernel<<<n4 / 256, 256, 0, stream>>>(
        (const float4*)x, (const float4*)reco, (float4*)updated);

    dim3 grid((N_DET + DET_TILE - 1) / DET_TILE, N_ANGLES);   // (12, 360)
    radon_kernel<<<grid, 512, 0, stream>>>(updated, angles, sino);
}